// Round 14
// baseline (97.318 us; speedup 1.0000x reference)
//
#include <hip/hip_runtime.h>
#include <hip/hip_bf16.h>

typedef _Float16 h4 __attribute__((ext_vector_type(4)));
typedef _Float16 h8 __attribute__((ext_vector_type(8)));
typedef float f32x4 __attribute__((ext_vector_type(4)));

#define CIN 128
#define COUT 256
#define KDIM (CIN*9)   // 1152

// ---------------- merged prep + transpose ----------------
// blocks [0,256): transpose  xT[((b*64+y)*64+x)*128 + c] = fp16(x[b][c][y][x])
// blocks [256,1408): Wf prep, SOURCE-indexed (coalesced wgt reads, scattered 2B writes)
// blocks [1408,1552): omWf prep
__global__ __launch_bounds__(256) void k_pt(const float* __restrict__ x,
                                            const float* __restrict__ wgt,
                                            const float* __restrict__ om_w,
                                            unsigned short* __restrict__ xT,
                                            unsigned short* __restrict__ Wf,
                                            unsigned short* __restrict__ omWf) {
    __shared__ unsigned short tile[64][132];
    const int bid = blockIdx.x;
    if (bid < 256) {
        const int b = bid >> 6, y = bid & 63;
        const float* xp = x + (size_t)b * CIN * 4096 + y * 64;
        const int w = threadIdx.x & 63, cg = threadIdx.x >> 6;
#pragma unroll
        for (int cc = 0; cc < CIN; cc += 4) {
            int c = cc + cg;
            _Float16 hv = (_Float16)xp[(size_t)c * 4096 + w];
            tile[w][c] = *(unsigned short*)&hv;
        }
        __syncthreads();
        unsigned short* orow = xT + (size_t)(b * 4096 + y * 64) * CIN;
#pragma unroll
        for (int i = 0; i < 8; ++i) {
            int j = threadIdx.x + i * 256;
            int w2 = j >> 5, c2 = (j & 31) * 4;
            ushort4 v = *(ushort4*)&tile[w2][c2];
            ((ushort4*)orow)[j] = v;
        }
    } else if (bid < 1408) {
        int g = (bid - 256) * 256 + threadIdx.x;      // < 294912
        int o = g / KDIM, rem = g - o * KDIM;
        int c = rem / 9, k = rem - c * 9;
        int kc = k * 128 + c;
        int kch = kc >> 5, j = kc & 31;
        int l = ((j >> 3) << 4) | (o & 15);
        int e = j & 7, of = o >> 4;
        int f = ((kch * 16 + of) * 64 + l) * 8 + e;
        _Float16 hv = (_Float16)wgt[g];
        Wf[f] = *(unsigned short*)&hv;
    } else {
        int f = (bid - 1408) * 256 + threadIdx.x;   // < 36864
        int e = f & 7, l = (f >> 3) & 63, of = (f >> 9) & 1, kch = f >> 10;
        int o = of * 16 + (l & 15);
        int c = (kch & 3) * 32 + (l >> 4) * 8 + e;
        int k = kch >> 2;
        float v = (o < 27) ? om_w[(size_t)o * KDIM + c * 9 + k] : 0.f;
        _Float16 hv = (_Float16)v;
        omWf[f] = *(unsigned short*)&hv;
    }
}

// ---------------- fused: offset-conv (MFMA) + gather + MFMA GEMM ----------------
// One block per (b, h, half): 32 positions x 256 Cout, 256 threads (4 waves).
// Phase 3: direct-to-register B-fragment gather; ZERO barriers, no LDS tile.
// Wave wv: positions (wv&1)*16 + (lane&15), Cout half (wv>>1)*128.
__global__ __launch_bounds__(256, 3) void k_fused(const unsigned short* __restrict__ xT_u,
                                                  const unsigned short* __restrict__ omWf_u,
                                                  const float* __restrict__ om_b,
                                                  const unsigned short* __restrict__ Wf_u,
                                                  const float* __restrict__ bias,
                                                  float* __restrict__ out) {
    const int bid = blockIdx.x;
    const int half = bid & 1, h = (bid >> 1) & 63, b = bid >> 7;
    const int p_base = half * 32;
    const int tid = threadIdx.x;
    const int wv = tid >> 6, lane = tid & 63;
    const int khalf = lane >> 4, lr = lane & 15;

    __shared__ int   s_off[4][288];
    __shared__ float s_wt[4][288];
    __shared__ float red[2][32][28];      // omconv partials [tapHalf][pos_local][oc]

    const _Float16* xb = (const _Float16*)xT_u + (size_t)b * (4096 * CIN);

    // ===== Phase 1: offset conv, 4 waves = 2 position-groups x 2 tap-halves =====
    {
        const h8* Af = (const h8*)omWf_u;
        const int pg = wv & 1, kh2 = wv >> 1;
        const int pl = pg * 16 + lr;               // local position 0..31
        const int p = p_base + pl;
        const int k0 = kh2 ? 5 : 0, k1 = kh2 ? 9 : 5;
        f32x4 acc0 = (f32x4){0.f, 0.f, 0.f, 0.f};
        f32x4 acc1 = (f32x4){0.f, 0.f, 0.f, 0.f};
        for (int k = k0; k < k1; ++k) {
            const int ky = k / 3, kx = k - ky * 3;
            const int y = h + ky - 1, xq = p + kx - 1;
            const bool valid = ((unsigned)y < 64u) && ((unsigned)xq < 64u);
            const _Float16* src = xb + ((y * 64 + xq) * CIN);
#pragma unroll
            for (int cg = 0; cg < 4; ++cg) {
                h8 bf = {};
                if (valid) bf = *(const h8*)(src + cg * 32 + khalf * 8);
                const int kch = k * 4 + cg;
                h8 a0 = Af[(kch * 2 + 0) * 64 + lane];
                h8 a1 = Af[(kch * 2 + 1) * 64 + lane];
                acc0 = __builtin_amdgcn_mfma_f32_16x16x32_f16(a0, bf, acc0, 0, 0, 0);
                acc1 = __builtin_amdgcn_mfma_f32_16x16x32_f16(a1, bf, acc1, 0, 0, 0);
            }
        }
#pragma unroll
        for (int r = 0; r < 4; ++r) {
            red[kh2][pl][khalf * 4 + r] = acc0[r];
            int row1 = 16 + khalf * 4 + r;
            if (row1 < 27) red[kh2][pl][row1] = acc1[r];
        }
    }
    __syncthreads();

    // ===== Phase 2: sampling metadata for all (tap, pl) =====
    for (int e = tid; e < 288; e += 256) {
        int k = e >> 5, pl = e & 31;
        int p = p_base + pl;
        float offx = red[0][pl][k]      + red[1][pl][k]      + om_b[k];
        float offy = red[0][pl][9 + k]  + red[1][pl][9 + k]  + om_b[9 + k];
        float mv   = red[0][pl][18 + k] + red[1][pl][18 + k] + om_b[18 + k];
        float mask = 1.f / (1.f + __expf(-mv));
        int ky = k / 3, kx = k - ky * 3;
        const float SC = 64.f / 63.f;
        float ix = ((float)(p + kx - 2) + offx) * SC - 0.5f;
        float iy = ((float)(h + ky - 2) + offy) * SC - 0.5f;
        float fx0 = floorf(ix), fy0 = floorf(iy);
        float wx1 = ix - fx0, wx0 = 1.f - wx1;
        float wy1 = iy - fy0, wy0 = 1.f - wy1;
        int x0 = (int)fx0, y0 = (int)fy0;
        int x1 = x0 + 1, y1 = y0 + 1;
        bool vx0 = (unsigned)x0 < 64u, vx1 = (unsigned)x1 < 64u;
        bool vy0 = (unsigned)y0 < 64u, vy1 = (unsigned)y1 < 64u;
        int xc0 = min(max(x0, 0), 63), xc1 = min(max(x1, 0), 63);
        int yc0 = min(max(y0, 0), 63), yc1 = min(max(y1, 0), 63);
        s_off[0][e] = (yc0 * 64 + xc0) * CIN;
        s_off[1][e] = (yc0 * 64 + xc1) * CIN;
        s_off[2][e] = (yc1 * 64 + xc0) * CIN;
        s_off[3][e] = (yc1 * 64 + xc1) * CIN;
        s_wt[0][e] = (vy0 && vx0) ? wy0 * wx0 * mask : 0.f;
        s_wt[1][e] = (vy0 && vx1) ? wy0 * wx1 * mask : 0.f;
        s_wt[2][e] = (vy1 && vx0) ? wy1 * wx0 * mask : 0.f;
        s_wt[3][e] = (vy1 && vx1) ? wy1 * wx1 * mask : 0.f;
    }
    __syncthreads();

    // ===== Phase 3: register-direct gather + MFMA, no barriers =====
    // Lane l gathers+blends 8 channels ((l>>4)*8..) of position (l&15):
    // that register IS the 16x16x32 B-fragment (B[k=(l>>4)*8+j][col=l&15]).
    {
        const int pg3 = wv & 1;               // position group
        const int oh  = wv >> 1;              // Cout half
        const int pl3 = pg3 * 16 + lr;        // this lane's position (local)
        const h8* Wf8 = (const h8*)Wf_u;

        f32x4 acc[8];
#pragma unroll
        for (int i = 0; i < 8; ++i) acc[i] = (f32x4){0.f, 0.f, 0.f, 0.f};

#pragma unroll 1
        for (int tap = 0; tap < 9; ++tap) {
            const int e = tap * 32 + pl3;
            const int o0 = s_off[0][e], o1 = s_off[1][e], o2 = s_off[2][e], o3 = s_off[3][e];
            const float m0 = s_wt[0][e], m1 = s_wt[1][e], m2 = s_wt[2][e], m3 = s_wt[3][e];
#pragma unroll 2
            for (int kg = 0; kg < 4; ++kg) {
                const int cb = kg * 32 + khalf * 8;
                h8 v0 = *(const h8*)(xb + o0 + cb);
                h8 v1 = *(const h8*)(xb + o1 + cb);
                h8 v2 = *(const h8*)(xb + o2 + cb);
                h8 v3 = *(const h8*)(xb + o3 + cb);
                h8 pk;
#pragma unroll
                for (int j = 0; j < 8; ++j) {
                    float r = m0 * (float)v0[j] + m1 * (float)v1[j]
                            + m2 * (float)v2[j] + m3 * (float)v3[j];
                    pk[j] = (_Float16)r;
                }
                const int kch = tap * 4 + kg;
#pragma unroll
                for (int i = 0; i < 8; ++i) {
                    h8 a = Wf8[(kch * 16 + oh * 8 + i) * 64 + lane];
                    acc[i] = __builtin_amdgcn_mfma_f32_16x16x32_f16(a, pk, acc[i], 0, 0, 0);
                }
            }
        }

        // epilogue: C[o = (oh*8+i)*16 + khalf*4 + r][pos = p_base + pg3*16 + lr]
        float* outb = out + (size_t)b * COUT * 4096 + h * 64 + p_base + pg3 * 16 + lr;
#pragma unroll
        for (int i = 0; i < 8; ++i) {
#pragma unroll
            for (int r = 0; r < 4; ++r) {
                const int o = (oh * 8 + i) * 16 + khalf * 4 + r;
                outb[(size_t)o * 4096] = acc[i][r] + bias[o];
            }
        }
    }
}

extern "C" void kernel_launch(void* const* d_in, const int* in_sizes, int n_in,
                              void* d_out, int out_size, void* d_ws, size_t ws_size,
                              hipStream_t stream) {
    const float* x    = (const float*)d_in[0];
    const float* om_w = (const float*)d_in[1];
    const float* om_b = (const float*)d_in[2];
    const float* wgt  = (const float*)d_in[3];
    const float* bias = (const float*)d_in[4];
    float* out = (float*)d_out;

    char* ws = (char*)d_ws;
    unsigned short* xT   = (unsigned short*)ws;                      // 4*4096*128*2 = 4194304 B
    unsigned short* Wf   = (unsigned short*)(ws + 4194304);          // 294912*2     =  589824 B
    unsigned short* omWf = (unsigned short*)(ws + 4194304 + 589824); // 36864*2      =   73728 B

    k_pt   <<<1552, 256, 0, stream>>>(x, wgt, om_w, xT, Wf, omWf);
    k_fused<<<512, 256, 0, stream>>>(xT, omWf, om_b, Wf, bias, out);
}

// Round 16
// 41.173 us; speedup vs baseline: 2.3636x; 2.3636x over previous
//
#include <hip/hip_runtime.h>
#include <hip/hip_bf16.h>

typedef _Float16 h4 __attribute__((ext_vector_type(4)));
typedef _Float16 h8 __attribute__((ext_vector_type(8)));
typedef float f32x4 __attribute__((ext_vector_type(4)));

#define CIN 128
#define COUT 256
#define KDIM (CIN*9)   // 1152

// ---------------- merged prep + transpose ----------------
// blocks [0,256): transpose  xT[((b*64+y)*64+x)*128 + c] = fp16(x[b][c][y][x])
// blocks [256,1408): Wf prep, SOURCE-indexed (coalesced wgt reads, scattered 2B writes)
// blocks [1408,1552): omWf prep
__global__ __launch_bounds__(256) void k_pt(const float* __restrict__ x,
                                            const float* __restrict__ wgt,
                                            const float* __restrict__ om_w,
                                            unsigned short* __restrict__ xT,
                                            unsigned short* __restrict__ Wf,
                                            unsigned short* __restrict__ omWf) {
    __shared__ unsigned short tile[64][132];
    const int bid = blockIdx.x;
    if (bid < 256) {
        const int b = bid >> 6, y = bid & 63;
        const float* xp = x + (size_t)b * CIN * 4096 + y * 64;
        const int w = threadIdx.x & 63, cg = threadIdx.x >> 6;
#pragma unroll
        for (int cc = 0; cc < CIN; cc += 4) {
            int c = cc + cg;
            _Float16 hv = (_Float16)xp[(size_t)c * 4096 + w];
            tile[w][c] = *(unsigned short*)&hv;
        }
        __syncthreads();
        unsigned short* orow = xT + (size_t)(b * 4096 + y * 64) * CIN;
#pragma unroll
        for (int i = 0; i < 8; ++i) {
            int j = threadIdx.x + i * 256;
            int w2 = j >> 5, c2 = (j & 31) * 4;
            ushort4 v = *(ushort4*)&tile[w2][c2];
            ((ushort4*)orow)[j] = v;
        }
    } else if (bid < 1408) {
        int g = (bid - 256) * 256 + threadIdx.x;      // < 294912
        int o = g / KDIM, rem = g - o * KDIM;
        int c = rem / 9, k = rem - c * 9;
        int kc = k * 128 + c;
        int kch = kc >> 5, j = kc & 31;
        int l = ((j >> 3) << 4) | (o & 15);
        int e = j & 7, of = o >> 4;
        int f = ((kch * 16 + of) * 64 + l) * 8 + e;
        _Float16 hv = (_Float16)wgt[g];
        Wf[f] = *(unsigned short*)&hv;
    } else {
        int f = (bid - 1408) * 256 + threadIdx.x;   // < 36864
        int e = f & 7, l = (f >> 3) & 63, of = (f >> 9) & 1, kch = f >> 10;
        int o = of * 16 + (l & 15);
        int c = (kch & 3) * 32 + (l >> 4) * 8 + e;
        int k = kch >> 2;
        float v = (o < 27) ? om_w[(size_t)o * KDIM + c * 9 + k] : 0.f;
        _Float16 hv = (_Float16)v;
        omWf[f] = *(unsigned short*)&hv;
    }
}

// ---------------- fused: offset-conv (MFMA) + gather + MFMA GEMM ----------------
// Block (b, h, half): 32 positions x 256 Cout, 512 threads (8 waves).
// Grid 512 x 8 waves -> 16 waves/CU (50% occupancy), 2 blocks/CU.
// Phase 3: R9-style double-buffered LDS pipeline, 9 chunks of 128 ch (one/tap),
// no gather duplication (each thread gathers once per chunk).
__global__ __launch_bounds__(512, 2) void k_fused(const unsigned short* __restrict__ xT_u,
                                                  const unsigned short* __restrict__ omWf_u,
                                                  const float* __restrict__ om_b,
                                                  const unsigned short* __restrict__ Wf_u,
                                                  const float* __restrict__ bias,
                                                  float* __restrict__ out) {
    const int bid = blockIdx.x;
    const int half = bid & 1, h = (bid >> 1) & 63, b = bid >> 7;
    const int p_base = half * 32;
    const int tid = threadIdx.x;
    const int wv = tid >> 6, lane = tid & 63;
    const int khalf = lane >> 4, lr = lane & 15;

    __shared__ int   s_off[4][288];
    __shared__ float s_wt[4][288];
    __shared__ h8    s_tile[2][32 * 16];  // [buf][row*16 + swizzled slot], 32 pos x 128 ch
    __shared__ float red[4][32][28];      // omconv partials [tapGroup][pos_local][oc]

    const _Float16* xb = (const _Float16*)xT_u + (size_t)b * (4096 * CIN);

    // ===== Phase 1: offset conv, 8 waves = 2 pos-groups x 4 tap-groups (3/2/2/2) =====
    {
        const h8* Af = (const h8*)omWf_u;
        const int pg = wv & 1, tg = wv >> 1;
        const int pl = pg * 16 + lr;               // local position 0..31
        const int p = p_base + pl;
        const int k0 = (tg == 0) ? 0 : 2 * tg + 1; // 0,3,5,7
        const int k1 = (tg == 0) ? 3 : k0 + 2;     // 3,5,7,9
        f32x4 acc0 = (f32x4){0.f, 0.f, 0.f, 0.f};
        f32x4 acc1 = (f32x4){0.f, 0.f, 0.f, 0.f};
        for (int k = k0; k < k1; ++k) {
            const int ky = k / 3, kx = k - ky * 3;
            const int y = h + ky - 1, xq = p + kx - 1;
            const bool valid = ((unsigned)y < 64u) && ((unsigned)xq < 64u);
            const _Float16* src = xb + ((y * 64 + xq) * CIN);
#pragma unroll
            for (int cg = 0; cg < 4; ++cg) {
                h8 bf = {};
                if (valid) bf = *(const h8*)(src + cg * 32 + khalf * 8);
                const int kch = k * 4 + cg;
                h8 a0 = Af[(kch * 2 + 0) * 64 + lane];
                h8 a1 = Af[(kch * 2 + 1) * 64 + lane];
                acc0 = __builtin_amdgcn_mfma_f32_16x16x32_f16(a0, bf, acc0, 0, 0, 0);
                acc1 = __builtin_amdgcn_mfma_f32_16x16x32_f16(a1, bf, acc1, 0, 0, 0);
            }
        }
        // C layout: col = lr (position), row = khalf*4 + r (+16 for acc1)
#pragma unroll
        for (int r = 0; r < 4; ++r) {
            red[tg][pl][khalf * 4 + r] = acc0[r];
            int row1 = 16 + khalf * 4 + r;
            if (row1 < 27) red[tg][pl][row1] = acc1[r];
        }
    }
    __syncthreads();

    // ===== Phase 2: sampling metadata for all (tap, pl) =====
    for (int e = tid; e < 288; e += 512) {
        int k = e >> 5, pl = e & 31;
        int p = p_base + pl;
        float offx = red[0][pl][k]      + red[1][pl][k]      + red[2][pl][k]      + red[3][pl][k]      + om_b[k];
        float offy = red[0][pl][9 + k]  + red[1][pl][9 + k]  + red[2][pl][9 + k]  + red[3][pl][9 + k]  + om_b[9 + k];
        float mv   = red[0][pl][18 + k] + red[1][pl][18 + k] + red[2][pl][18 + k] + red[3][pl][18 + k] + om_b[18 + k];
        float mask = 1.f / (1.f + __expf(-mv));
        int ky = k / 3, kx = k - ky * 3;
        const float SC = 64.f / 63.f;
        float ix = ((float)(p + kx - 2) + offx) * SC - 0.5f;
        float iy = ((float)(h + ky - 2) + offy) * SC - 0.5f;
        float fx0 = floorf(ix), fy0 = floorf(iy);
        float wx1 = ix - fx0, wx0 = 1.f - wx1;
        float wy1 = iy - fy0, wy0 = 1.f - wy1;
        int x0 = (int)fx0, y0 = (int)fy0;
        int x1 = x0 + 1, y1 = y0 + 1;
        bool vx0 = (unsigned)x0 < 64u, vx1 = (unsigned)x1 < 64u;
        bool vy0 = (unsigned)y0 < 64u, vy1 = (unsigned)y1 < 64u;
        int xc0 = min(max(x0, 0), 63), xc1 = min(max(x1, 0), 63);
        int yc0 = min(max(y0, 0), 63), yc1 = min(max(y1, 0), 63);
        s_off[0][e] = (yc0 * 64 + xc0) * CIN;
        s_off[1][e] = (yc0 * 64 + xc1) * CIN;
        s_off[2][e] = (yc1 * 64 + xc0) * CIN;
        s_off[3][e] = (yc1 * 64 + xc1) * CIN;
        s_wt[0][e] = (vy0 && vx0) ? wy0 * wx0 * mask : 0.f;
        s_wt[1][e] = (vy0 && vx1) ? wy0 * wx1 * mask : 0.f;
        s_wt[2][e] = (vy1 && vx0) ? wy1 * wx0 * mask : 0.f;
        s_wt[3][e] = (vy1 && vx1) ? wy1 * wx1 * mask : 0.f;
    }
    __syncthreads();

    // ===== Phase 3: pipelined gather + MFMA GEMM (9 chunks of 128 ch, 1 chunk/tap) =====
    // Gather: thread (p = tid>>4, ci = tid&15) -> 4 corner loads, blend, one LDS write.
    // Write slot = ci ^ (p&7); read slot = (ks*4+khalf) ^ (row&7).
    // Each wave: 32 Cout (wv*32) x 32 pos; per kch: 2 a-loads + 2 ds_reads + 4 MFMAs.
    const int p  = tid >> 4;      // local gather position 0..31
    const int ci = tid & 15;      // 8-channel slot 0..15
    const h8* Wf8 = (const h8*)Wf_u;
    const int wslot = ci ^ (p & 7);

    f32x4 acc[2][2];              // [Cout-frag i][pos-frag pf]
#pragma unroll
    for (int i = 0; i < 2; ++i)
#pragma unroll
        for (int j = 0; j < 2; ++j) acc[i][j] = (f32x4){0.f, 0.f, 0.f, 0.f};

    // prologue: gather chunk 0 (tap 0) into buf 0
    {
        const int e0 = p;
        const int cb = ci * 8;
        h8 v0 = *(const h8*)(xb + s_off[0][e0] + cb);
        h8 v1 = *(const h8*)(xb + s_off[1][e0] + cb);
        h8 v2 = *(const h8*)(xb + s_off[2][e0] + cb);
        h8 v3 = *(const h8*)(xb + s_off[3][e0] + cb);
        const float m0 = s_wt[0][e0], m1 = s_wt[1][e0], m2 = s_wt[2][e0], m3 = s_wt[3][e0];
        h8 pk;
#pragma unroll
        for (int j = 0; j < 8; ++j) {
            float r = m0 * (float)v0[j] + m1 * (float)v1[j]
                    + m2 * (float)v2[j] + m3 * (float)v3[j];
            pk[j] = (_Float16)r;
        }
        s_tile[0][p * 16 + wslot] = pk;
    }
    __syncthreads();

    for (int tap = 0; tap < 9; ++tap) {
        const int cur = tap & 1;
        const int nxt = tap + 1;

        // issue next-chunk gathers early (latency hides under 16 MFMAs)
        h8 v0, v1, v2, v3;
        float m0, m1, m2, m3;
        if (nxt < 9) {
            const int e = nxt * 32 + p;
            const int cb = ci * 8;
            v0 = *(const h8*)(xb + s_off[0][e] + cb);
            v1 = *(const h8*)(xb + s_off[1][e] + cb);
            v2 = *(const h8*)(xb + s_off[2][e] + cb);
            v3 = *(const h8*)(xb + s_off[3][e] + cb);
            m0 = s_wt[0][e]; m1 = s_wt[1][e]; m2 = s_wt[2][e]; m3 = s_wt[3][e];
        }

        // 16 MFMAs on current chunk (4 kch of 32 ch)
#pragma unroll
        for (int ks = 0; ks < 4; ++ks) {
            const int kch = tap * 4 + ks;
            h8 a0 = Wf8[(kch * 16 + wv * 2 + 0) * 64 + lane];
            h8 a1 = Wf8[(kch * 16 + wv * 2 + 1) * 64 + lane];
#pragma unroll
            for (int pf = 0; pf < 2; ++pf) {
                const int row = pf * 16 + lr;
                const int slot = (ks * 4 + khalf) ^ (row & 7);
                h8 bf = s_tile[cur][row * 16 + slot];
                acc[0][pf] = __builtin_amdgcn_mfma_f32_16x16x32_f16(a0, bf, acc[0][pf], 0, 0, 0);
                acc[1][pf] = __builtin_amdgcn_mfma_f32_16x16x32_f16(a1, bf, acc[1][pf], 0, 0, 0);
            }
        }

        // blend + write next chunk to the other buffer
        if (nxt < 9) {
            h8 pk;
#pragma unroll
            for (int j = 0; j < 8; ++j) {
                float r = m0 * (float)v0[j] + m1 * (float)v1[j]
                        + m2 * (float)v2[j] + m3 * (float)v3[j];
                pk[j] = (_Float16)r;
            }
            s_tile[cur ^ 1][p * 16 + wslot] = pk;
        }
        __syncthreads();
    }

    // epilogue: C[o = wv*32 + i*16 + khalf*4 + r][pos = p_base + pf*16 + lr]
    float* outb = out + (size_t)b * COUT * 4096 + h * 64 + p_base;
#pragma unroll
    for (int i = 0; i < 2; ++i) {
#pragma unroll
        for (int r = 0; r < 4; ++r) {
            const int o = wv * 32 + i * 16 + khalf * 4 + r;
            const float bo = bias[o];
            float* orow = outb + (size_t)o * 4096;
#pragma unroll
            for (int pf = 0; pf < 2; ++pf)
                orow[pf * 16 + lr] = acc[i][pf][r] + bo;
        }
    }
}

extern "C" void kernel_launch(void* const* d_in, const int* in_sizes, int n_in,
                              void* d_out, int out_size, void* d_ws, size_t ws_size,
                              hipStream_t stream) {
    const float* x    = (const float*)d_in[0];
    const float* om_w = (const float*)d_in[1];
    const float* om_b = (const float*)d_in[2];
    const float* wgt  = (const float*)d_in[3];
    const float* bias = (const float*)d_in[4];
    float* out = (float*)d_out;

    char* ws = (char*)d_ws;
    unsigned short* xT   = (unsigned short*)ws;                      // 4*4096*128*2 = 4194304 B
    unsigned short* Wf   = (unsigned short*)(ws + 4194304);          // 294912*2     =  589824 B
    unsigned short* omWf = (unsigned short*)(ws + 4194304 + 589824); // 36864*2      =   73728 B

    k_pt   <<<1552, 256, 0, stream>>>(x, wgt, om_w, xT, Wf, omWf);
    k_fused<<<512, 512, 0, stream>>>(xT, omWf, om_b, Wf, bias, out);
}

// Round 18
// 39.947 us; speedup vs baseline: 2.4362x; 1.0307x over previous
//
#include <hip/hip_runtime.h>
#include <hip/hip_bf16.h>

typedef _Float16 h4 __attribute__((ext_vector_type(4)));
typedef _Float16 h8 __attribute__((ext_vector_type(8)));
typedef float f32x4 __attribute__((ext_vector_type(4)));

#define CIN 128
#define COUT 256
#define KDIM (CIN*9)   // 1152

// ---------------- merged prep + transpose ----------------
// blocks [0,256): transpose  xT[((b*64+y)*64+x)*128 + c] = fp16(x[b][c][y][x])
// blocks [256,1408): Wf prep, SOURCE-indexed (coalesced wgt reads, scattered 2B writes)
// blocks [1408,1552): omWf prep
__global__ __launch_bounds__(256) void k_pt(const float* __restrict__ x,
                                            const float* __restrict__ wgt,
                                            const float* __restrict__ om_w,
                                            unsigned short* __restrict__ xT,
                                            unsigned short* __restrict__ Wf,
                                            unsigned short* __restrict__ omWf) {
    __shared__ unsigned short tile[64][132];
    const int bid = blockIdx.x;
    if (bid < 256) {
        const int b = bid >> 6, y = bid & 63;
        const float* xp = x + (size_t)b * CIN * 4096 + y * 64;
        const int w = threadIdx.x & 63, cg = threadIdx.x >> 6;
#pragma unroll
        for (int cc = 0; cc < CIN; cc += 4) {
            int c = cc + cg;
            _Float16 hv = (_Float16)xp[(size_t)c * 4096 + w];
            tile[w][c] = *(unsigned short*)&hv;
        }
        __syncthreads();
        unsigned short* orow = xT + (size_t)(b * 4096 + y * 64) * CIN;
#pragma unroll
        for (int i = 0; i < 8; ++i) {
            int j = threadIdx.x + i * 256;
            int w2 = j >> 5, c2 = (j & 31) * 4;
            ushort4 v = *(ushort4*)&tile[w2][c2];
            ((ushort4*)orow)[j] = v;
        }
    } else if (bid < 1408) {
        int g = (bid - 256) * 256 + threadIdx.x;      // < 294912
        int o = g / KDIM, rem = g - o * KDIM;
        int c = rem / 9, k = rem - c * 9;
        int kc = k * 128 + c;
        int kch = kc >> 5, j = kc & 31;
        int l = ((j >> 3) << 4) | (o & 15);
        int e = j & 7, of = o >> 4;
        int f = ((kch * 16 + of) * 64 + l) * 8 + e;
        _Float16 hv = (_Float16)wgt[g];
        Wf[f] = *(unsigned short*)&hv;
    } else {
        int f = (bid - 1408) * 256 + threadIdx.x;   // < 36864
        int e = f & 7, l = (f >> 3) & 63, of = (f >> 9) & 1, kch = f >> 10;
        int o = of * 16 + (l & 15);
        int c = (kch & 3) * 32 + (l >> 4) * 8 + e;
        int k = kch >> 2;
        float v = (o < 27) ? om_w[(size_t)o * KDIM + c * 9 + k] : 0.f;
        _Float16 hv = (_Float16)v;
        omWf[f] = *(unsigned short*)&hv;
    }
}

// ---------------- fused: offset-conv (MFMA) + gather + MFMA GEMM ----------------
// Block (b, h): full row, 64 positions x 256 Cout, 1024 threads (16 waves).
// Grid 256 -> 1 block/CU, 16 waves/CU (4/SIMD) — same occupancy as R16 but
// Wf L2 traffic HALVED (256 blocks x 9 chunks x 64 KB = 147 MB vs 295 MB).
// Phase 3: double-buffered LDS pipeline, 9 chunks of 128 ch (one per tap).
__global__ __launch_bounds__(1024, 4) void k_fused(const unsigned short* __restrict__ xT_u,
                                                   const unsigned short* __restrict__ omWf_u,
                                                   const float* __restrict__ om_b,
                                                   const unsigned short* __restrict__ Wf_u,
                                                   const float* __restrict__ bias,
                                                   float* __restrict__ out) {
    const int bid = blockIdx.x;
    const int h = bid & 63, b = bid >> 6;
    const int tid = threadIdx.x;
    const int wv = tid >> 6, lane = tid & 63;
    const int khalf = lane >> 4, lr = lane & 15;   // khalf in 0..3

    __shared__ int   s_off[4][576];
    __shared__ float s_wt[4][576];
    __shared__ h8    s_tile[2][64 * 16];  // [buf][row*16 + swizzled slot], 64 pos x 128 ch
    __shared__ float red[4][64][28];      // omconv partials [tapGroup][pos][oc]

    const _Float16* xb = (const _Float16*)xT_u + (size_t)b * (4096 * CIN);

    // ===== Phase 1: offset conv, 16 waves = 4 pos-groups x 4 tap-groups (3/2/2/2) =====
    {
        const h8* Af = (const h8*)omWf_u;
        const int pg = wv & 3, tg = wv >> 2;
        const int pl = pg * 16 + lr;               // position 0..63
        const int k0 = (tg == 0) ? 0 : 2 * tg + 1; // 0,3,5,7
        const int k1 = (tg == 0) ? 3 : k0 + 2;     // 3,5,7,9
        f32x4 acc0 = (f32x4){0.f, 0.f, 0.f, 0.f};
        f32x4 acc1 = (f32x4){0.f, 0.f, 0.f, 0.f};
        for (int k = k0; k < k1; ++k) {
            const int ky = k / 3, kx = k - ky * 3;
            const int y = h + ky - 1, xq = pl + kx - 1;
            const bool valid = ((unsigned)y < 64u) && ((unsigned)xq < 64u);
            const _Float16* src = xb + ((y * 64 + xq) * CIN);
#pragma unroll
            for (int cg = 0; cg < 4; ++cg) {
                h8 bf = {};
                if (valid) bf = *(const h8*)(src + cg * 32 + khalf * 8);
                const int kch = k * 4 + cg;
                h8 a0 = Af[(kch * 2 + 0) * 64 + lane];
                h8 a1 = Af[(kch * 2 + 1) * 64 + lane];
                acc0 = __builtin_amdgcn_mfma_f32_16x16x32_f16(a0, bf, acc0, 0, 0, 0);
                acc1 = __builtin_amdgcn_mfma_f32_16x16x32_f16(a1, bf, acc1, 0, 0, 0);
            }
        }
        // C layout: col = lr (position), row = khalf*4 + r (+16 for acc1)
#pragma unroll
        for (int r = 0; r < 4; ++r) {
            red[tg][pl][khalf * 4 + r] = acc0[r];
            int row1 = 16 + khalf * 4 + r;
            if (row1 < 27) red[tg][pl][row1] = acc1[r];
        }
    }
    __syncthreads();

    // ===== Phase 2: sampling metadata for all (tap, p) =====
    for (int e = tid; e < 576; e += 1024) {
        int k = e >> 6, p = e & 63;
        float offx = red[0][p][k]      + red[1][p][k]      + red[2][p][k]      + red[3][p][k]      + om_b[k];
        float offy = red[0][p][9 + k]  + red[1][p][9 + k]  + red[2][p][9 + k]  + red[3][p][9 + k]  + om_b[9 + k];
        float mv   = red[0][p][18 + k] + red[1][p][18 + k] + red[2][p][18 + k] + red[3][p][18 + k] + om_b[18 + k];
        float mask = 1.f / (1.f + __expf(-mv));
        int ky = k / 3, kx = k - ky * 3;
        const float SC = 64.f / 63.f;
        float ix = ((float)(p + kx - 2) + offx) * SC - 0.5f;
        float iy = ((float)(h + ky - 2) + offy) * SC - 0.5f;
        float fx0 = floorf(ix), fy0 = floorf(iy);
        float wx1 = ix - fx0, wx0 = 1.f - wx1;
        float wy1 = iy - fy0, wy0 = 1.f - wy1;
        int x0 = (int)fx0, y0 = (int)fy0;
        int x1 = x0 + 1, y1 = y0 + 1;
        bool vx0 = (unsigned)x0 < 64u, vx1 = (unsigned)x1 < 64u;
        bool vy0 = (unsigned)y0 < 64u, vy1 = (unsigned)y1 < 64u;
        int xc0 = min(max(x0, 0), 63), xc1 = min(max(x1, 0), 63);
        int yc0 = min(max(y0, 0), 63), yc1 = min(max(y1, 0), 63);
        s_off[0][e] = (yc0 * 64 + xc0) * CIN;
        s_off[1][e] = (yc0 * 64 + xc1) * CIN;
        s_off[2][e] = (yc1 * 64 + xc0) * CIN;
        s_off[3][e] = (yc1 * 64 + xc1) * CIN;
        s_wt[0][e] = (vy0 && vx0) ? wy0 * wx0 * mask : 0.f;
        s_wt[1][e] = (vy0 && vx1) ? wy0 * wx1 * mask : 0.f;
        s_wt[2][e] = (vy1 && vx0) ? wy1 * wx0 * mask : 0.f;
        s_wt[3][e] = (vy1 && vx1) ? wy1 * wx1 * mask : 0.f;
    }
    __syncthreads();

    // ===== Phase 3: pipelined gather + MFMA GEMM (9 chunks of 128 ch, 1/tap) =====
    // Gather: thread (p = tid>>4, ci = tid&15) -> 4 corner loads, blend, 1 LDS write.
    // Write slot = ci ^ (p&7); read slot = (ks*4+khalf) ^ (row&7).
    // Wave wv owns Cout frag wv (rows wv*16..+15) x 64 pos: per kch 1 a-load + 4 ds_reads + 4 MFMAs.
    const int p  = tid >> 4;      // gather position 0..63
    const int ci = tid & 15;      // 8-channel slot 0..15
    const h8* Wf8 = (const h8*)Wf_u;
    const int wslot = ci ^ (p & 7);

    f32x4 acc[4];                 // [pos-frag pf]
#pragma unroll
    for (int j = 0; j < 4; ++j) acc[j] = (f32x4){0.f, 0.f, 0.f, 0.f};

    // prologue: gather chunk 0 (tap 0) into buf 0
    {
        const int e0 = p;
        const int cb = ci * 8;
        h8 v0 = *(const h8*)(xb + s_off[0][e0] + cb);
        h8 v1 = *(const h8*)(xb + s_off[1][e0] + cb);
        h8 v2 = *(const h8*)(xb + s_off[2][e0] + cb);
        h8 v3 = *(const h8*)(xb + s_off[3][e0] + cb);
        const float m0 = s_wt[0][e0], m1 = s_wt[1][e0], m2 = s_wt[2][e0], m3 = s_wt[3][e0];
        h8 pk;
#pragma unroll
        for (int j = 0; j < 8; ++j) {
            float r = m0 * (float)v0[j] + m1 * (float)v1[j]
                    + m2 * (float)v2[j] + m3 * (float)v3[j];
            pk[j] = (_Float16)r;
        }
        s_tile[0][p * 16 + wslot] = pk;
    }
    __syncthreads();

    for (int tap = 0; tap < 9; ++tap) {
        const int cur = tap & 1;
        const int nxt = tap + 1;

        // issue next-chunk gathers early (latency hides under 16 MFMAs)
        h8 v0, v1, v2, v3;
        float m0, m1, m2, m3;
        if (nxt < 9) {
            const int e = nxt * 64 + p;
            const int cb = ci * 8;
            v0 = *(const h8*)(xb + s_off[0][e] + cb);
            v1 = *(const h8*)(xb + s_off[1][e] + cb);
            v2 = *(const h8*)(xb + s_off[2][e] + cb);
            v3 = *(const h8*)(xb + s_off[3][e] + cb);
            m0 = s_wt[0][e]; m1 = s_wt[1][e]; m2 = s_wt[2][e]; m3 = s_wt[3][e];
        }

        // 16 MFMAs on current chunk (4 kch of 32 ch x 4 pos-frags)
#pragma unroll
        for (int ks = 0; ks < 4; ++ks) {
            const int kch = tap * 4 + ks;
            h8 a0 = Wf8[(kch * 16 + wv) * 64 + lane];
#pragma unroll
            for (int pf = 0; pf < 4; ++pf) {
                const int row = pf * 16 + lr;
                const int slot = (ks * 4 + khalf) ^ (row & 7);
                h8 bf = s_tile[cur][row * 16 + slot];
                acc[pf] = __builtin_amdgcn_mfma_f32_16x16x32_f16(a0, bf, acc[pf], 0, 0, 0);
            }
        }

        // blend + write next chunk to the other buffer
        if (nxt < 9) {
            h8 pk;
#pragma unroll
            for (int j = 0; j < 8; ++j) {
                float r = m0 * (float)v0[j] + m1 * (float)v1[j]
                        + m2 * (float)v2[j] + m3 * (float)v3[j];
                pk[j] = (_Float16)r;
            }
            s_tile[cur ^ 1][p * 16 + wslot] = pk;
        }
        __syncthreads();
    }

    // epilogue: C[o = wv*16 + khalf*4 + r][pos = pf*16 + lr]
    float* outb = out + (size_t)b * COUT * 4096 + h * 64;
#pragma unroll
    for (int r = 0; r < 4; ++r) {
        const int o = wv * 16 + khalf * 4 + r;
        const float bo = bias[o];
        float* orow = outb + (size_t)o * 4096;
#pragma unroll
        for (int pf = 0; pf < 4; ++pf)
            orow[pf * 16 + lr] = acc[pf][r] + bo;
    }
}

extern "C" void kernel_launch(void* const* d_in, const int* in_sizes, int n_in,
                              void* d_out, int out_size, void* d_ws, size_t ws_size,
                              hipStream_t stream) {
    const float* x    = (const float*)d_in[0];
    const float* om_w = (const float*)d_in[1];
    const float* om_b = (const float*)d_in[2];
    const float* wgt  = (const float*)d_in[3];
    const float* bias = (const float*)d_in[4];
    float* out = (float*)d_out;

    char* ws = (char*)d_ws;
    unsigned short* xT   = (unsigned short*)ws;                      // 4*4096*128*2 = 4194304 B
    unsigned short* Wf   = (unsigned short*)(ws + 4194304);          // 294912*2     =  589824 B
    unsigned short* omWf = (unsigned short*)(ws + 4194304 + 589824); // 36864*2      =   73728 B

    k_pt   <<<1552, 256, 0, stream>>>(x, wgt, om_w, xT, Wf, omWf);
    k_fused<<<256, 1024, 0, stream>>>(xT, omWf, om_b, Wf, bias, out);
}